// Round 15
// baseline (209.297 us; speedup 1.0000x reference)
//
#include <hip/hip_runtime.h>
#include <math.h>

// QNN: all gates are GF(2)-convolutions and the CNOT cascade is a linear bit
// permutation P  =>  the 16 initial basis states evolve into XOR-translates
// of ONE simulated state: probs_j(i) = probs_0(i ^ P^4(j)).
// Simulate a single 2^18 complex state (2 MB), then
// logits[j][o] = sum_d probs_0(d ^ T_j) * W[o][d] + b[o];  (MFMA, bf16)
// out[b][o] = sigmoid(logits[idx_b][o]).
//
// SINGLE persistent kernel (256 blocks = 1/CU, co-resident by capacity):
// 6 circuit phases + k_mm (CPB=8) + finalize, separated by 7 flag-release
// grid barriers. Graph = memset(bar) + k_all = 2 nodes (was 8).
//
// Bit convention: wire w <-> bit p = 17-w.  P: out bit q (q<=16) =
// parity(i>>q); out bit 17 = parity(i & 0x1FFFF).
// Gate split per layer: A = bits {0..8,17} (10 gates, P folded into load),
// BC = bits {9..16} (8 gates, natural in-place write).

#define DIM (1 << 18)
#define NW 18
#define CH 128                      // k_mm d-columns per LDS stage
#define CPB 8                       // chunks per k_mm block
#define NMM 256                     // k_mm blocks / partial rows

#define PAD16(i) ((i) + ((i) >> 4))

typedef short short8 __attribute__((ext_vector_type(8)));   // 8 bf16 (4 VGPRs)
typedef float f32x4  __attribute__((ext_vector_type(4)));   // MFMA accumulator

__device__ __forceinline__ unsigned perm18(unsigned i) {
    unsigned s = i;
    s ^= s >> 1; s ^= s >> 2; s ^= s >> 4; s ^= s >> 8; s ^= s >> 16;
    unsigned out = s & 0x1FFFFu;
    out |= ((s ^ (i >> 17)) & 1u) << 17;
    return out;
}

__device__ __forceinline__ unsigned pinv18(unsigned b) {
    unsigned t = b & 0x1FFFFu;
    unsigned u = (t ^ (t >> 1)) & 0xFFFFu;
    unsigned i17 = ((b >> 17) ^ t) & 1u;
    unsigned i16 = ((t >> 16) ^ i17) & 1u;
    return u | (i16 << 16) | (i17 << 17);
}

__device__ __forceinline__ unsigned ginv9(unsigned x) {     // inverse Gray, 9b
    x ^= x >> 1; x ^= x >> 2; x ^= x >> 4; x ^= x >> 8;
    return x & 511u;
}

__device__ __forceinline__ void bfly(float2& a0, float2& a1, float c, float s) {
    float2 n0 = make_float2(c * a0.x + s * a1.y, c * a0.y - s * a1.x);
    float2 n1 = make_float2(c * a1.x + s * a0.y, c * a1.y - s * a0.x);
    a0 = n0; a1 = n1;
}

__device__ __forceinline__ short f2bf(float x) {            // RNE fp32->bf16
    unsigned u = __float_as_uint(x);
    return (short)((u + 0x7FFFu + ((u >> 16) & 1u)) >> 16);
}

// grid barrier: per-phase arrival counter + single release flag (written once;
// waiters poll the flag only). RMW release-sequence gives agent-scope
// visibility of all blocks' prior writes (pattern correctness-proven in R5).
__device__ __forceinline__ void gbar(unsigned* bar, int k) {
    __syncthreads();
    if (threadIdx.x == 0) {
        unsigned old = __hip_atomic_fetch_add(bar + 2 + k, 1u,
                                              __ATOMIC_ACQ_REL, __HIP_MEMORY_SCOPE_AGENT);
        if (old == 255u) {
            __hip_atomic_store(bar, (unsigned)(k + 1),
                               __ATOMIC_RELEASE, __HIP_MEMORY_SCOPE_AGENT);
        } else {
            while (__hip_atomic_load(bar, __ATOMIC_ACQUIRE,
                                     __HIP_MEMORY_SCOPE_AGENT) < (unsigned)(k + 1))
                __builtin_amdgcn_s_sleep(1);
        }
    }
    __syncthreads();
}

// 2-gate register round on slot bits (RB, RB+1) of a 1024-slot LDS tile.
template<int RB>
__device__ __forceinline__ void slotRound(float2* t, int m, float2 g0, float2 g1) {
    constexpr int B = 1 << RB;
    int low = m & (B - 1);
    int high = m >> RB;
    int ib = (high << (RB + 2)) | low;
    int p00 = PAD16(ib), p01 = PAD16(ib | B), p10 = PAD16(ib | 2 * B), p11 = PAD16(ib | 3 * B);
    float2 e00 = t[p00], e01 = t[p01], e10 = t[p10], e11 = t[p11];
    bfly(e00, e01, g0.x, g0.y);
    bfly(e10, e11, g0.x, g0.y);
    bfly(e00, e10, g1.x, g1.y);
    bfly(e01, e11, g1.x, g1.y);
    t[p00] = e00; t[p01] = e01; t[p10] = e10; t[p11] = e11;
}

// shared tail for A-phases: rounds on slot bits (1,2),(3,4),(5,6),(7,8)+write.
__device__ __forceinline__ void kaTail(float2* t, int tid, const float2* gsh,
                                       float2* __restrict__ out, unsigned B9) {
    slotRound<1>(t, tid, gsh[1], gsh[2]); __syncthreads();
    slotRound<3>(t, tid, gsh[3], gsh[4]); __syncthreads();
    slotRound<5>(t, tid, gsh[5], gsh[6]); __syncthreads();
    int low = tid & 127, high = tid >> 7;      // high = p17
    int ib = (high << 9) | low;
    float2 a0 = t[PAD16(ib)], a1 = t[PAD16(ib | 128)];
    float2 a2 = t[PAD16(ib | 256)], a3 = t[PAD16(ib | 384)];
    bfly(a0, a1, gsh[7].x, gsh[7].y);
    bfly(a2, a3, gsh[7].x, gsh[7].y);
    bfly(a0, a2, gsh[8].x, gsh[8].y);
    bfly(a1, a3, gsh[8].x, gsh[8].y);
    unsigned ob = ((unsigned)high << 17) | (B9 << 9) | (unsigned)low;
    out[ob] = a0; out[ob + 128] = a1; out[ob + 256] = a2; out[ob + 384] = a3;
}

// ---- phase: analytic layer-0 (post-P basis) + layer-1 gates {0..8,17} ------
__device__ void ph_init(float2* t, float2* gsh, float2* __restrict__ out, const float* qw) {
    int tid = threadIdx.x;
    if (tid < 10) {
        int p = (tid == 9) ? 17 : tid;
        float th = qw[1 * NW + (17 - p)] * 0.5f;
        gsh[tid] = make_float2(cosf(th), sinf(th));
    }
    float c[NW], s[NW];
#pragma unroll
    for (int w = 0; w < NW; ++w) {
        float th = qw[w] * 0.5f;
        c[w] = cosf(th); s[w] = sinf(th);
    }
    unsigned B9 = blockIdx.x;
    float2 e[2][2];
#pragma unroll
    for (int p17 = 0; p17 < 2; ++p17)
#pragma unroll
        for (int b0 = 0; b0 < 2; ++b0) {
            unsigned b = ((unsigned)p17 << 17) | (B9 << 9) | ((unsigned)tid << 1) | (unsigned)b0;
            unsigned i = pinv18(b);
            float m = 1.0f;
#pragma unroll
            for (int p = 0; p < 18; ++p)
                m *= ((i >> p) & 1u) ? s[17 - p] : c[17 - p];
            int k4 = __popc(i) & 3;
            if      (k4 == 0) e[p17][b0] = make_float2( m, 0.f);
            else if (k4 == 1) e[p17][b0] = make_float2(0.f, -m);
            else if (k4 == 2) e[p17][b0] = make_float2(-m, 0.f);
            else              e[p17][b0] = make_float2(0.f,  m);
        }
    __syncthreads();
    bfly(e[0][0], e[0][1], gsh[0].x, gsh[0].y);
    bfly(e[1][0], e[1][1], gsh[0].x, gsh[0].y);
    bfly(e[0][0], e[1][0], gsh[9].x, gsh[9].y);
    bfly(e[0][1], e[1][1], gsh[9].x, gsh[9].y);
    int sb = tid << 1;
    t[PAD16(sb)] = e[0][0];       t[PAD16(sb | 1)] = e[0][1];
    t[PAD16(sb | 512)] = e[1][0]; t[PAD16(sb | 513)] = e[1][1];
    __syncthreads();
    kaTail(t, tid, gsh, out, B9);
}

// ---- phase: P-folded gather + 10 gates {0..8,17}, natural write ------------
__device__ void ph_a(float2* t, float2* gsh, const float2* __restrict__ in,
                     float2* __restrict__ out, const float* qw, int layer) {
    int tid = threadIdx.x;
    if (tid < 10) {
        int p = (tid == 9) ? 17 : tid;
        float th = qw[layer * NW + (17 - p)] * 0.5f;
        gsh[tid] = make_float2(cosf(th), sinf(th));
    }
    unsigned B9 = blockIdx.x;
    unsigned C = pinv18(B9 << 9);
    unsigned c9 = C & 511u;
    unsigned base0 = C & ~511u;
    unsigned base1 = base0 ^ 0x30000u;
    float2 v[2][2];
#pragma unroll
    for (int ee = 0; ee < 2; ++ee)
#pragma unroll
        for (int r = 0; r < 2; ++r)
            v[ee][r] = in[(ee ? base1 : base0) + (unsigned)tid + 256u * r];
#pragma unroll
    for (int ee = 0; ee < 2; ++ee)
#pragma unroll
        for (int r = 0; r < 2; ++r) {
            unsigned k = (unsigned)tid + 256u * r;
            unsigned x = (k ^ c9) & 511u;
            unsigned bl = ginv9(x);
            unsigned p17 = ((unsigned)__popc(x) ^ (unsigned)ee) & 1u;
            t[PAD16((p17 << 9) | bl)] = v[ee][r];
        }
    __syncthreads();
    {
        int s00 = tid << 1;
        int p00 = PAD16(s00), p01 = PAD16(s00 | 1), p10 = PAD16(s00 | 512), p11 = PAD16(s00 | 513);
        float2 e00 = t[p00], e01 = t[p01], e10 = t[p10], e11 = t[p11];
        bfly(e00, e01, gsh[0].x, gsh[0].y);
        bfly(e10, e11, gsh[0].x, gsh[0].y);
        bfly(e00, e10, gsh[9].x, gsh[9].y);
        bfly(e01, e11, gsh[9].x, gsh[9].y);
        t[p00] = e00; t[p01] = e01; t[p10] = e10; t[p11] = e11;
    }
    __syncthreads();
    kaTail(t, tid, gsh, out, B9);
}

// ---- phase: 8 RX gates on bits 9..16, natural in-place (or probs scatter) --
__device__ void ph_bc(float2* t, float2* gsh, float2* __restrict__ buf, float* probs,
                      const float* qw, int layer) {
    int tid = threadIdx.x;
    if (tid < 8) {
        float th = qw[layer * NW + (8 - tid)] * 0.5f;
        gsh[tid] = make_float2(cosf(th), sinf(th));
    }
    unsigned blk = blockIdx.x;
    unsigned ibase = ((blk >> 7) << 17) | ((blk & 127u) << 2);
    int mh = tid >> 2, lo = tid & 3;
    ibase |= (unsigned)lo;
    float2 e0 = buf[((unsigned)(4 * mh + 0) << 9) | ibase];
    float2 e1 = buf[((unsigned)(4 * mh + 1) << 9) | ibase];
    float2 e2 = buf[((unsigned)(4 * mh + 2) << 9) | ibase];
    float2 e3 = buf[((unsigned)(4 * mh + 3) << 9) | ibase];
    __syncthreads();
    bfly(e0, e1, gsh[0].x, gsh[0].y);
    bfly(e2, e3, gsh[0].x, gsh[0].y);
    bfly(e0, e2, gsh[1].x, gsh[1].y);
    bfly(e1, e3, gsh[1].x, gsh[1].y);
    {
        int k = 4 * (4 * mh) + lo;
        t[PAD16(k)] = e0; t[PAD16(k + 4)] = e1; t[PAD16(k + 8)] = e2; t[PAD16(k + 12)] = e3;
    }
    __syncthreads();
    {
        int hb = ((mh >> 2) << 4) | (mh & 3);
        int p00 = PAD16(4 * hb + lo), p01 = PAD16(4 * (hb | 4) + lo);
        int p10 = PAD16(4 * (hb | 8) + lo), p11 = PAD16(4 * (hb | 12) + lo);
        float2 a0 = t[p00], a1 = t[p01], a2 = t[p10], a3 = t[p11];
        bfly(a0, a1, gsh[2].x, gsh[2].y);
        bfly(a2, a3, gsh[2].x, gsh[2].y);
        bfly(a0, a2, gsh[3].x, gsh[3].y);
        bfly(a1, a3, gsh[3].x, gsh[3].y);
        t[p00] = a0; t[p01] = a1; t[p10] = a2; t[p11] = a3;
    }
    __syncthreads();
    {
        int hb = ((mh >> 4) << 6) | (mh & 15);
        int p00 = PAD16(4 * hb + lo), p01 = PAD16(4 * (hb | 16) + lo);
        int p10 = PAD16(4 * (hb | 32) + lo), p11 = PAD16(4 * (hb | 48) + lo);
        float2 a0 = t[p00], a1 = t[p01], a2 = t[p10], a3 = t[p11];
        bfly(a0, a1, gsh[4].x, gsh[4].y);
        bfly(a2, a3, gsh[4].x, gsh[4].y);
        bfly(a0, a2, gsh[5].x, gsh[5].y);
        bfly(a1, a3, gsh[5].x, gsh[5].y);
        t[p00] = a0; t[p01] = a1; t[p10] = a2; t[p11] = a3;
    }
    __syncthreads();
    {
        int k = 4 * mh + lo;
        float2 a0 = t[PAD16(k)], a1 = t[PAD16(k + 256)], a2 = t[PAD16(k + 512)], a3 = t[PAD16(k + 768)];
        bfly(a0, a1, gsh[6].x, gsh[6].y);
        bfly(a2, a3, gsh[6].x, gsh[6].y);
        bfly(a0, a2, gsh[7].x, gsh[7].y);
        bfly(a1, a3, gsh[7].x, gsh[7].y);
        unsigned i0 = ((unsigned)(mh +   0) << 9) | ibase;
        unsigned i1 = ((unsigned)(mh +  64) << 9) | ibase;
        unsigned i2 = ((unsigned)(mh + 128) << 9) | ibase;
        unsigned i3 = ((unsigned)(mh + 192) << 9) | ibase;
        if (probs) {
            probs[perm18(i0)] = a0.x * a0.x + a0.y * a0.y;
            probs[perm18(i1)] = a1.x * a1.x + a1.y * a1.y;
            probs[perm18(i2)] = a2.x * a2.x + a2.y * a2.y;
            probs[perm18(i3)] = a3.x * a3.x + a3.y * a3.y;
        } else {
            buf[i0] = a0; buf[i1] = a1; buf[i2] = a2; buf[i3] = a3;
        }
    }
}

// ---- phase: logits partials via MFMA, 256 blocks x 8 chunks ---------------
__device__ void ph_mm(char* ldsraw, const float* __restrict__ p0,
                      const float* __restrict__ W, float* __restrict__ partial) {
    short (*Wl)[136] = (short(*)[136])ldsraw;                 // 17408 B
    short (*Pl)[136] = (short(*)[136])(ldsraw + 17408);       //  4352 B
    unsigned* Tsh    = (unsigned*)(ldsraw + 21760);           //    64 B
    int tid = threadIdx.x;
    if (tid < 16) {
        unsigned v = (unsigned)tid;
#pragma unroll
        for (int r = 0; r < 4; ++r) v = perm18(v);
        Tsh[tid] = v;
    }
    __syncthreads();

    unsigned d00 = (unsigned)blockIdx.x * (CH * CPB);
    int wrow = tid >> 5;
    int wcol = (tid & 31) * 4;
    int prow = tid >> 7;
    int pcol = tid & 127;
    unsigned Tp[8];
#pragma unroll
    for (int t = 0; t < 8; ++t) Tp[t] = Tsh[prow + 2 * t];

    int lane = tid & 63, wv = tid >> 6;
    int arow = lane & 15, kg = (lane >> 4) * 8;
    f32x4 acc = {0.f, 0.f, 0.f, 0.f};

    float4 wr[8];
    float  pr[8];

#pragma unroll
    for (int t = 0; t < 8; ++t)
        wr[t] = *(const float4*)&W[(size_t)(wrow + 8 * t) * DIM + d00 + wcol];
#pragma unroll
    for (int t = 0; t < 8; ++t)
        pr[t] = p0[(d00 ^ (Tp[t] & ~127u)) + pcol];
#pragma unroll
    for (int t = 0; t < 8; ++t) {
        short4 b = make_short4(f2bf(wr[t].x), f2bf(wr[t].y), f2bf(wr[t].z), f2bf(wr[t].w));
        *(short4*)&Wl[wrow + 8 * t][wcol] = b;
    }
#pragma unroll
    for (int t = 0; t < 8; ++t)
        Pl[prow + 2 * t][pcol ^ (Tp[t] & 127u)] = f2bf(pr[t]);
    __syncthreads();

    for (int cc = 0; cc < CPB; ++cc) {
        if (cc + 1 < CPB) {
            unsigned d1 = d00 + (unsigned)(cc + 1) * CH;
#pragma unroll
            for (int t = 0; t < 8; ++t)
                wr[t] = *(const float4*)&W[(size_t)(wrow + 8 * t) * DIM + d1 + wcol];
#pragma unroll
            for (int t = 0; t < 8; ++t)
                pr[t] = p0[(d1 ^ (Tp[t] & ~127u)) + pcol];
        }
#pragma unroll
        for (int kk = 0; kk < 4; ++kk) {
            short8 a = *(const short8*)&Pl[arow][kk * 32 + kg];
            short8 b = *(const short8*)&Wl[16 * wv + arow][kk * 32 + kg];
            acc = __builtin_amdgcn_mfma_f32_16x16x32_bf16(a, b, acc, 0, 0, 0);
        }
        __syncthreads();
        if (cc + 1 < CPB) {
#pragma unroll
            for (int t = 0; t < 8; ++t) {
                short4 b = make_short4(f2bf(wr[t].x), f2bf(wr[t].y), f2bf(wr[t].z), f2bf(wr[t].w));
                *(short4*)&Wl[wrow + 8 * t][wcol] = b;
            }
#pragma unroll
            for (int t = 0; t < 8; ++t)
                Pl[prow + 2 * t][pcol ^ (Tp[t] & 127u)] = f2bf(pr[t]);
            __syncthreads();
        }
    }

    float* dst = partial + (size_t)blockIdx.x * 1024;
#pragma unroll
    for (int r = 0; r < 4; ++r) {
        int jrow = (lane >> 4) * 4 + r;
        dst[jrow * 64 + 16 * wv + (lane & 15)] = acc[r];
    }
}

// ---- phase: reduce partials -> logits; lookup + sigmoid (blocks 0..63) -----
__device__ void ph_fin(char* ldsraw, const float* __restrict__ partial,
                       const float* __restrict__ bias, const int* __restrict__ x,
                       float* __restrict__ out) {
    float (*red)[17] = (float(*)[17])ldsraw;                  // 1088 B
    float* lg        = (float*)(ldsraw + 1152);               //   64 B
    int*   sidx      = (int*)(ldsraw + 1280);                 //  128 B
    int b = blockIdx.x;
    int tid = threadIdx.x;
    int ji = tid & 15, ci = tid >> 4;
    int jo = b * 16 + ji;
    float sum = 0.f;
#pragma unroll 8
    for (int c = ci; c < NMM; c += 16)
        sum += partial[(size_t)c * 1024 + jo];
    red[ci][ji] = sum;
    if (tid < 32) {
        const int* xb = x + (size_t)tid * (16384 * 4);
        sidx[tid] = 8 * xb[0] + 4 * xb[1] + 2 * xb[2] + xb[3];
    }
    __syncthreads();
    if (ci == 0) {
        float s = 0.f;
#pragma unroll
        for (int k = 0; k < 16; ++k) s += red[k][ji];
        lg[ji] = s + bias[jo & 63];
    }
    __syncthreads();
    int myidx = b >> 2, o0 = (b & 3) * 16;
#pragma unroll
    for (int r = 0; r < 2; ++r) {
        int slot = tid + 256 * r;
        int bb = slot >> 4, k = slot & 15;
        if (sidx[bb] == myidx) {
            float z = lg[k];
            out[bb * 64 + o0 + k] = 1.f / (1.f + expf(-z));
        }
    }
}

// ---- the single persistent kernel ------------------------------------------
__global__ __launch_bounds__(256) void k_all(const float* __restrict__ qw,
                                             const float* __restrict__ W,
                                             const int* __restrict__ x,
                                             const float* __restrict__ bias,
                                             float2* buf0, float2* buf1,
                                             float* probs, float* partial,
                                             float* out, unsigned* bar) {
    __shared__ __align__(16) char ldsraw[21888];
    float2* t   = (float2*)ldsraw;                  // 1088 float2 = 8704 B
    float2* gsh = (float2*)(ldsraw + 8704);         // 10 float2

    ph_init(t, gsh, buf0, qw);                      // L0 analytic + L1 {0..8,17}
    gbar(bar, 0);
    ph_bc(t, gsh, buf0, nullptr, qw, 1);            // L1 {9..16}, in-place
    gbar(bar, 1);
    ph_a(t, gsh, buf0, buf1, qw, 2);                // P-gather + L2 {0..8,17}
    gbar(bar, 2);
    ph_bc(t, gsh, buf1, nullptr, qw, 2);            // L2 {9..16}, in-place
    gbar(bar, 3);
    ph_a(t, gsh, buf1, buf0, qw, 3);                // P-gather + L3 {0..8,17}
    gbar(bar, 4);
    ph_bc(t, gsh, buf0, probs, qw, 3);              // L3 {9..16} + P-scatter probs
    gbar(bar, 5);
    ph_mm(ldsraw, probs, W, partial);               // MFMA logits partials
    gbar(bar, 6);
    if (blockIdx.x < 64)
        ph_fin(ldsraw, partial, bias, x, out);
}

extern "C" void kernel_launch(void* const* d_in, const int* in_sizes, int n_in,
                              void* d_out, int out_size, void* d_ws, size_t ws_size,
                              hipStream_t stream) {
    const int*   x    = (const int*)d_in[0];
    const float* qw   = (const float*)d_in[1];
    const float* W    = (const float*)d_in[2];
    const float* bias = (const float*)d_in[3];
    float* out = (float*)d_out;

    char* ws = (char*)d_ws;
    unsigned* bar     = (unsigned*)ws;                     // 9+ words
    float2*   buf0    = (float2*)(ws + (1ull << 20));      // 2 MB
    float2*   buf1    = (float2*)(ws + (4ull << 20));      // 2 MB
    float*    probs   = (float*)(ws + (8ull << 20));       // 1 MB
    float*    partial = (float*)(ws + (16ull << 20));      // 1 MB

    hipMemsetAsync(bar, 0, 256, stream);
    k_all<<<256, 256, 0, stream>>>(qw, W, x, bias, buf0, buf1, probs, partial, out, bar);
}

// Round 16
// 70.606 us; speedup vs baseline: 2.9643x; 2.9643x over previous
//
#include <hip/hip_runtime.h>
#include <math.h>

// QNN. Storage basis = post-P1. All 54 RX gates are (c I - i s X_D) with
// XOR-masks D; they ALL COMMUTE. Conjugated masks: L1: e_p; L2: D1_q =
// pinv(e_q); L3: D2_q = pinv^2(e_q). Verified vs the passing R14 kernel
// (same operators, applied there via physical P-gathers).
//   D1: q=0:{0,16,17}, 1<=q<=15:{q-1,q,16,17}, 16:{15,17}, 17:{16,17}
//   D2: q=0:{0,15,17}, 1:{1,15,16}, 2..14:{q-2,q,15,16}, 15:{13,16},
//       16:{14,15}, 17:{15,16}
// Two passes cover all: X1 span {0..8,15,16,17} (33 gates + analytic init),
// X2 span {7..17} (21 gates + |amp|^2 + P^3 scatter to probs).
// k_mm (MFMA) + finalize fused via last-64-blocks ticket. 3 graph nodes.

#define DIM (1 << 18)
#define NW 18
#define CH 128
#define CPB 4
#define NMM 512
#define PAD16(i) ((i) + ((i) >> 4))

typedef short short8 __attribute__((ext_vector_type(8)));
typedef float f32x4  __attribute__((ext_vector_type(4)));

__device__ __forceinline__ unsigned perm18(unsigned i) {
    unsigned s = i;
    s ^= s >> 1; s ^= s >> 2; s ^= s >> 4; s ^= s >> 8; s ^= s >> 16;
    unsigned out = s & 0x1FFFFu;
    out |= ((s ^ (i >> 17)) & 1u) << 17;
    return out;
}
__device__ __forceinline__ unsigned pinv18(unsigned b) {
    unsigned t = b & 0x1FFFFu;
    unsigned u = (t ^ (t >> 1)) & 0xFFFFu;
    unsigned i17 = ((b >> 17) ^ t) & 1u;
    unsigned i16 = ((t >> 16) ^ i17) & 1u;
    return u | (i16 << 16) | (i17 << 17);
}
__device__ __forceinline__ void bfly(float2& a0, float2& a1, float c, float s) {
    float2 n0 = make_float2(c * a0.x + s * a1.y, c * a0.y - s * a1.x);
    float2 n1 = make_float2(c * a1.x + s * a0.y, c * a1.y - s * a0.x);
    a0 = n0; a1 = n1;
}
__device__ __forceinline__ short f2bf(float x) {
    unsigned u = __float_as_uint(x);
    return (short)((u + 0x7FFFu + ((u >> 16) & 1u)) >> 16);
}

// X1 local bits: r0..8 = global 0..8; r9,r10,r11 = global 15,16,17.
// angle index = l*18 + (17 - bit).
__device__ const unsigned X1M[33] = {
    0x001,0x002,0x004,0x008,0x010,0x020,0x040,0x080,0x100,0x200,0x400,0x800, // L1 p=0..8,15,16,17
    0xC01,0xC03,0xC06,0xC0C,0xC18,0xC30,0xC60,0xCC0,0xD80,0xA00,0xC00,       // L2 q=0..8,16,17
    0xA01,0x602,0x605,0x60A,0x614,0x628,0x650,0x6A0,0x740,0x600};            // L3 q=0..8,17
__device__ const unsigned char X1A[33] = {
    35,34,33,32,31,30,29,28,27,20,19,18,
    53,52,51,50,49,48,47,46,45,37,36,
    71,70,69,68,67,66,65,64,63,54};
// X2 local bits: r = global - 7.
__device__ const unsigned X2M[21] = {
    0x004,0x008,0x010,0x020,0x040,0x080,                 // L1 p=9..14
    0x606,0x60C,0x618,0x630,0x660,0x6C0,0x780,           // L2 q=9..15
    0x305,0x30A,0x314,0x328,0x350,0x3A0,0x240,0x180};    // L3 q=9..15,16 (q15={13,16}->0x240, q16={14,15}->0x180)
__device__ const unsigned char X2A[21] = {
    26,25,24,23,22,21,
    44,43,42,41,40,39,38,
    62,61,60,59,58,57,56,55};

// two commuting gates per round: orbit {i, i^M1, i^M2p, i^M1^M2p}
__device__ __forceinline__ void pairRound(float2* t, int T, unsigned M1, unsigned M2,
                                          float2 g1, float2 g2) {
    unsigned z1 = M1 & (0u - M1);
    bool sw = (M2 & z1) != 0u;
    unsigned M2p = sw ? (M1 ^ M2) : M2;
    unsigned z2 = M2p & (0u - M2p);
    unsigned zl = z1 < z2 ? z1 : z2, zh = z1 < z2 ? z2 : z1;
    int pl = 31 - __clz(zl), ph = 31 - __clz(zh);
    for (int k = threadIdx.x; k < T / 4; k += 256) {
        unsigned i = (((unsigned)k >> pl) << (pl + 1)) | ((unsigned)k & (zl - 1u));
        i = ((i >> ph) << (ph + 1)) | (i & (zh - 1u));
        int iA = PAD16((int)i), iB = PAD16((int)(i ^ M1));
        int iC = PAD16((int)(i ^ M2p)), iD = PAD16((int)(i ^ M1 ^ M2p));
        float2 A = t[iA], B = t[iB], C = t[iC], D = t[iD];
        bfly(A, B, g1.x, g1.y); bfly(C, D, g1.x, g1.y);
        if (sw) { bfly(A, D, g2.x, g2.y); bfly(B, C, g2.x, g2.y); }
        else    { bfly(A, C, g2.x, g2.y); bfly(B, D, g2.x, g2.y); }
        t[iA] = A; t[iB] = B; t[iC] = C; t[iD] = D;
    }
}
__device__ __forceinline__ void singleRound(float2* t, int T, unsigned M, float2 g) {
    unsigned z = M & (0u - M);
    int p = 31 - __clz(z);
    for (int k = threadIdx.x; k < T / 2; k += 256) {
        unsigned i = (((unsigned)k >> p) << (p + 1)) | ((unsigned)k & (z - 1u));
        int i0 = PAD16((int)i), i1 = PAD16((int)(i ^ M));
        float2 A = t[i0], B = t[i1];
        bfly(A, B, g.x, g.y);
        t[i0] = A; t[i1] = B;
    }
}

// ---- X1: analytic init + 33 gates on span {0..8,15,16,17}; 64 blocks ------
__global__ __launch_bounds__(256) void kX1(float2* __restrict__ out, const float* __restrict__ qw) {
    __shared__ float2 t[4352];
    __shared__ float2 g[33];
    int tid = threadIdx.x;
    if (tid < 33) { float th = qw[X1A[tid]] * 0.5f; g[tid] = make_float2(cosf(th), sinf(th)); }
    float c0[NW], s0[NW];
#pragma unroll
    for (int w = 0; w < NW; ++w) { float th = qw[w] * 0.5f; c0[w] = cosf(th); s0[w] = sinf(th); }
    unsigned blk = blockIdx.x;                 // global bits 9..14
#pragma unroll
    for (int r = 0; r < 16; ++r) {
        int l = tid + 256 * r;
        unsigned b = ((unsigned)l & 511u) | (blk << 9) | (((unsigned)l >> 9) << 15);
        unsigned i = pinv18(b);
        float m = 1.f;
#pragma unroll
        for (int p = 0; p < 18; ++p) m *= ((i >> p) & 1u) ? s0[17 - p] : c0[17 - p];
        int k4 = __popc(i) & 3;
        float2 a;
        if      (k4 == 0) a = make_float2( m, 0.f);
        else if (k4 == 1) a = make_float2(0.f, -m);
        else if (k4 == 2) a = make_float2(-m, 0.f);
        else              a = make_float2(0.f,  m);
        t[PAD16(l)] = a;
    }
    __syncthreads();
#pragma unroll
    for (int gi = 0; gi < 32; gi += 2) {
        pairRound(t, 4096, X1M[gi], X1M[gi + 1], g[gi], g[gi + 1]);
        __syncthreads();
    }
    singleRound(t, 4096, X1M[32], g[32]);
    __syncthreads();
#pragma unroll
    for (int r = 0; r < 16; ++r) {
        int l = tid + 256 * r;
        unsigned b = ((unsigned)l & 511u) | (blk << 9) | (((unsigned)l >> 9) << 15);
        out[b] = t[PAD16(l)];
    }
}

// ---- X2: 21 gates on span {7..17} + |amp|^2 + P^3 scatter; 128 blocks -----
__global__ __launch_bounds__(256) void kX2(const float2* __restrict__ in, float* __restrict__ probs,
                                           const float* __restrict__ qw, unsigned* __restrict__ ctr) {
    __shared__ float2 t[2176];
    __shared__ float2 g[21];
    int tid = threadIdx.x;
    if (tid < 21) { float th = qw[X2A[tid]] * 0.5f; g[tid] = make_float2(cosf(th), sinf(th)); }
    if (blockIdx.x == 0 && tid == 0)
        __hip_atomic_store(ctr, 0u, __ATOMIC_RELAXED, __HIP_MEMORY_SCOPE_AGENT);
    unsigned blk = blockIdx.x;                 // global bits 0..6
#pragma unroll
    for (int r = 0; r < 8; ++r) {
        int l = tid + 256 * r;
        t[PAD16(l)] = in[blk | ((unsigned)l << 7)];
    }
    __syncthreads();
#pragma unroll
    for (int gi = 0; gi < 20; gi += 2) {
        pairRound(t, 2048, X2M[gi], X2M[gi + 1], g[gi], g[gi + 1]);
        __syncthreads();
    }
    singleRound(t, 2048, X2M[20], g[20]);
    __syncthreads();
#pragma unroll
    for (int r = 0; r < 8; ++r) {
        int l = tid + 256 * r;
        unsigned b = blk | ((unsigned)l << 7);
        unsigned pb = perm18(perm18(perm18(b)));
        float2 a = t[PAD16(l)];
        probs[pb] = a.x * a.x + a.y * a.y;
    }
}

// ---- k_mm (R14-proven) + fused finalize via last-64 ticket ----------------
__global__ __launch_bounds__(256) void k_mm(const float* __restrict__ p0,
                                            const float* __restrict__ W,
                                            float* __restrict__ partial,
                                            const int* __restrict__ x,
                                            const float* __restrict__ bias,
                                            float* __restrict__ out,
                                            unsigned* __restrict__ ctr) {
    __shared__ short Wl[64][136];
    __shared__ short Pl[16][136];
    __shared__ unsigned Tsh[16];
    __shared__ unsigned tik;
    __shared__ float red[16][17];
    __shared__ float lg[16];
    __shared__ int sidx[32];
    int tid = threadIdx.x;
    if (tid < 16) {
        unsigned v = (unsigned)tid;
#pragma unroll
        for (int r = 0; r < 4; ++r) v = perm18(v);
        Tsh[tid] = v;
    }
    __syncthreads();

    unsigned d00 = (unsigned)blockIdx.x * (CH * CPB);
    int wrow = tid >> 5;
    int wcol = (tid & 31) * 4;
    int prow = tid >> 7;
    int pcol = tid & 127;
    unsigned Tp[8];
#pragma unroll
    for (int t = 0; t < 8; ++t) Tp[t] = Tsh[prow + 2 * t];

    int lane = tid & 63, wv = tid >> 6;
    int arow = lane & 15, kg = (lane >> 4) * 8;
    f32x4 acc = {0.f, 0.f, 0.f, 0.f};
    float4 wr[8];
    float  pr[8];

#pragma unroll
    for (int t = 0; t < 8; ++t)
        wr[t] = *(const float4*)&W[(size_t)(wrow + 8 * t) * DIM + d00 + wcol];
#pragma unroll
    for (int t = 0; t < 8; ++t)
        pr[t] = p0[(d00 ^ (Tp[t] & ~127u)) + pcol];
#pragma unroll
    for (int t = 0; t < 8; ++t) {
        short4 b = make_short4(f2bf(wr[t].x), f2bf(wr[t].y), f2bf(wr[t].z), f2bf(wr[t].w));
        *(short4*)&Wl[wrow + 8 * t][wcol] = b;
    }
#pragma unroll
    for (int t = 0; t < 8; ++t)
        Pl[prow + 2 * t][pcol ^ (Tp[t] & 127u)] = f2bf(pr[t]);
    __syncthreads();

    for (int cc = 0; cc < CPB; ++cc) {
        if (cc + 1 < CPB) {
            unsigned d1 = d00 + (unsigned)(cc + 1) * CH;
#pragma unroll
            for (int t = 0; t < 8; ++t)
                wr[t] = *(const float4*)&W[(size_t)(wrow + 8 * t) * DIM + d1 + wcol];
#pragma unroll
            for (int t = 0; t < 8; ++t)
                pr[t] = p0[(d1 ^ (Tp[t] & ~127u)) + pcol];
        }
#pragma unroll
        for (int kk = 0; kk < 4; ++kk) {
            short8 a = *(const short8*)&Pl[arow][kk * 32 + kg];
            short8 b = *(const short8*)&Wl[16 * wv + arow][kk * 32 + kg];
            acc = __builtin_amdgcn_mfma_f32_16x16x32_bf16(a, b, acc, 0, 0, 0);
        }
        __syncthreads();
        if (cc + 1 < CPB) {
#pragma unroll
            for (int t = 0; t < 8; ++t) {
                short4 b = make_short4(f2bf(wr[t].x), f2bf(wr[t].y), f2bf(wr[t].z), f2bf(wr[t].w));
                *(short4*)&Wl[wrow + 8 * t][wcol] = b;
            }
#pragma unroll
            for (int t = 0; t < 8; ++t)
                Pl[prow + 2 * t][pcol ^ (Tp[t] & 127u)] = f2bf(pr[t]);
            __syncthreads();
        }
    }

    // partial write-through (bypass L2) so finishers can read via L3
    float* dst = partial + (size_t)blockIdx.x * 1024;
#pragma unroll
    for (int r = 0; r < 4; ++r) {
        int jrow = (lane >> 4) * 4 + r;
        __hip_atomic_store(&dst[jrow * 64 + 16 * wv + (lane & 15)], acc[r],
                           __ATOMIC_RELAXED, __HIP_MEMORY_SCOPE_AGENT);
    }
    __syncthreads();   // all waves drain vmem before ticket (waitcnt before barrier)

    if (tid == 0)
        tik = __hip_atomic_fetch_add(ctr, 1u, __ATOMIC_RELEASE, __HIP_MEMORY_SCOPE_AGENT);
    __syncthreads();
    unsigned ticket = tik;
    if (ticket < (unsigned)(NMM - 64)) return;
    int b = (int)(ticket - (NMM - 64));       // finalize slice 0..63

    if (tid == 0) {
        while (__hip_atomic_load(ctr, __ATOMIC_RELAXED, __HIP_MEMORY_SCOPE_AGENT) < (unsigned)NMM)
            __builtin_amdgcn_s_sleep(4);
    }
    __syncthreads();

    int ji = tid & 15, ci = tid >> 4;
    int jo = b * 16 + ji;
    float sum = 0.f;
#pragma unroll 8
    for (int c = ci; c < NMM; c += 16)
        sum += __hip_atomic_load(&partial[(size_t)c * 1024 + jo],
                                 __ATOMIC_RELAXED, __HIP_MEMORY_SCOPE_AGENT);
    red[ci][ji] = sum;
    if (tid < 32) {
        const int* xb = x + (size_t)tid * (16384 * 4);
        sidx[tid] = 8 * xb[0] + 4 * xb[1] + 2 * xb[2] + xb[3];
    }
    __syncthreads();
    if (ci == 0) {
        float s = 0.f;
#pragma unroll
        for (int k = 0; k < 16; ++k) s += red[k][ji];
        lg[ji] = s + bias[jo & 63];
    }
    __syncthreads();
    int myidx = b >> 2, o0 = (b & 3) * 16;
#pragma unroll
    for (int r = 0; r < 2; ++r) {
        int slot = tid + 256 * r;
        int bb = slot >> 4, k = slot & 15;
        if (sidx[bb] == myidx) {
            float z = lg[k];
            out[bb * 64 + o0 + k] = 1.f / (1.f + expf(-z));
        }
    }
}

extern "C" void kernel_launch(void* const* d_in, const int* in_sizes, int n_in,
                              void* d_out, int out_size, void* d_ws, size_t ws_size,
                              hipStream_t stream) {
    const int*   x    = (const int*)d_in[0];
    const float* qw   = (const float*)d_in[1];
    const float* W    = (const float*)d_in[2];
    const float* bias = (const float*)d_in[3];
    float* out = (float*)d_out;

    char* ws = (char*)d_ws;
    unsigned* ctr     = (unsigned*)ws;
    float2*   buf0    = (float2*)(ws + (1ull << 20));      // 2 MB
    float*    probs   = (float*)(ws + (8ull << 20));       // 1 MB
    float*    partial = (float*)(ws + (16ull << 20));      // 2 MB

    kX1<<<64, 256, 0, stream>>>(buf0, qw);
    kX2<<<128, 256, 0, stream>>>(buf0, probs, qw, ctr);
    k_mm<<<NMM, 256, 0, stream>>>(probs, W, partial, x, bias, out, ctr);
}

// Round 17
// 52.148 us; speedup vs baseline: 4.0135x; 1.3540x over previous
//
#include <hip/hip_runtime.h>
#include <math.h>

// QNN. Storage basis = post-P1. All 54 RX gates are (c I - i s X_D) with
// XOR-masks D; they ALL COMMUTE (X_D are XOR-shifts). Conjugated masks
// (HW-verified in R16, absmax 0): L1: e_p; L2: pinv(e_q); L3: pinv^2(e_q).
// Two passes: X1 span {0..8,15,16,17} (33 gates + analytic init, 64 blk x
// 1024 thr), X2 span {7..17} (21 gates + |amp|^2 + P^3 scatter, 128 x 512).
// Then R14-proven k_mm (MFMA) + k_finalize. 4 graph nodes.

#define DIM (1 << 18)
#define NW 18
#define CH 128
#define CPB 4
#define NMM 512
#define PAD16(i) ((i) + ((i) >> 4))

typedef short short8 __attribute__((ext_vector_type(8)));
typedef float f32x4  __attribute__((ext_vector_type(4)));

__device__ __forceinline__ unsigned perm18(unsigned i) {
    unsigned s = i;
    s ^= s >> 1; s ^= s >> 2; s ^= s >> 4; s ^= s >> 8; s ^= s >> 16;
    unsigned out = s & 0x1FFFFu;
    out |= ((s ^ (i >> 17)) & 1u) << 17;
    return out;
}
__device__ __forceinline__ unsigned pinv18(unsigned b) {
    unsigned t = b & 0x1FFFFu;
    unsigned u = (t ^ (t >> 1)) & 0xFFFFu;
    unsigned i17 = ((b >> 17) ^ t) & 1u;
    unsigned i16 = ((t >> 16) ^ i17) & 1u;
    return u | (i16 << 16) | (i17 << 17);
}
__device__ __forceinline__ void bfly(float2& a0, float2& a1, float c, float s) {
    float2 n0 = make_float2(c * a0.x + s * a1.y, c * a0.y - s * a1.x);
    float2 n1 = make_float2(c * a1.x + s * a0.y, c * a1.y - s * a0.x);
    a0 = n0; a1 = n1;
}
__device__ __forceinline__ short f2bf(float x) {
    unsigned u = __float_as_uint(x);
    return (short)((u + 0x7FFFu + ((u >> 16) & 1u)) >> 16);
}

// masks/angles (R16 HW-verified). X1 local bits: r0..8=g0..8, r9..11=g15..17.
constexpr unsigned cX1M[33] = {
    0x001,0x002,0x004,0x008,0x010,0x020,0x040,0x080,0x100,0x200,0x400,0x800,
    0xC01,0xC03,0xC06,0xC0C,0xC18,0xC30,0xC60,0xCC0,0xD80,0xA00,0xC00,
    0xA01,0x602,0x605,0x60A,0x614,0x628,0x650,0x6A0,0x740,0x600};
constexpr unsigned char cX1A[33] = {
    35,34,33,32,31,30,29,28,27,20,19,18,
    53,52,51,50,49,48,47,46,45,37,36,
    71,70,69,68,67,66,65,64,63,54};
// X2 local bits: r = g - 7.
constexpr unsigned cX2M[21] = {
    0x004,0x008,0x010,0x020,0x040,0x080,
    0x606,0x60C,0x618,0x630,0x660,0x6C0,0x780,
    0x305,0x30A,0x314,0x328,0x350,0x3A0,0x240,0x180};
constexpr unsigned char cX2A[21] = {
    26,25,24,23,22,21,
    44,43,42,41,40,39,38,
    62,61,60,59,58,57,56,55};

constexpr int ctzc(unsigned x) { int n = 0; while (!(x & 1u)) { x >>= 1; ++n; } return n; }

// two commuting gates per round, ALL indices compile-time.
template<unsigned M1, unsigned M2, int T, int NT>
__device__ __forceinline__ void pairR(float2* t, float2 g1, float2 g2) {
    constexpr unsigned z1 = M1 & (0u - M1);
    constexpr bool sw = (M2 & z1) != 0u;
    constexpr unsigned M2p = sw ? (M1 ^ M2) : M2;
    constexpr unsigned z2 = M2p & (0u - M2p);
    constexpr unsigned zl = (z1 < z2) ? z1 : z2;
    constexpr unsigned zh = (z1 < z2) ? z2 : z1;
    constexpr int pl = ctzc(zl);
    constexpr int ph = ctzc(zh);
#pragma unroll
    for (int it = 0; it < (T / 4) / NT; ++it) {
        unsigned k = (unsigned)threadIdx.x + (unsigned)(it * NT);
        unsigned i = ((k >> pl) << (pl + 1)) | (k & (zl - 1u));
        i = ((i >> ph) << (ph + 1)) | (i & (zh - 1u));
        int iA = PAD16((int)i), iB = PAD16((int)(i ^ M1));
        int iC = PAD16((int)(i ^ M2p)), iD = PAD16((int)(i ^ M1 ^ M2p));
        float2 A = t[iA], B = t[iB], C = t[iC], D = t[iD];
        bfly(A, B, g1.x, g1.y); bfly(C, D, g1.x, g1.y);
        if (sw) { bfly(A, D, g2.x, g2.y); bfly(B, C, g2.x, g2.y); }
        else    { bfly(A, C, g2.x, g2.y); bfly(B, D, g2.x, g2.y); }
        t[iA] = A; t[iB] = B; t[iC] = C; t[iD] = D;
    }
}
template<unsigned M, int T, int NT>
__device__ __forceinline__ void singleR(float2* t, float2 g) {
    constexpr unsigned z = M & (0u - M);
    constexpr int p = ctzc(z);
#pragma unroll
    for (int it = 0; it < (T / 2) / NT; ++it) {
        unsigned k = (unsigned)threadIdx.x + (unsigned)(it * NT);
        unsigned i = ((k >> p) << (p + 1)) | (k & (z - 1u));
        int i0 = PAD16((int)i), i1 = PAD16((int)(i ^ M));
        float2 A = t[i0], B = t[i1];
        bfly(A, B, g.x, g.y);
        t[i0] = A; t[i1] = B;
    }
}

// ---- X1: analytic init + 33 gates on span {0..8,15,16,17}; 64 x 1024 ------
__global__ __launch_bounds__(1024) void kX1(float2* __restrict__ out, const float* __restrict__ qw) {
    __shared__ float2 t[4352];
    __shared__ float2 g[33];
    int tid = threadIdx.x;
    if (tid < 33) { float th = qw[cX1A[tid]] * 0.5f; g[tid] = make_float2(cosf(th), sinf(th)); }
    float c0[NW], s0[NW];
#pragma unroll
    for (int w = 0; w < NW; ++w) { float th = qw[w] * 0.5f; c0[w] = cosf(th); s0[w] = sinf(th); }
    unsigned blk = blockIdx.x;                 // global bits 9..14
#pragma unroll
    for (int r = 0; r < 4; ++r) {
        int l = tid + 1024 * r;
        unsigned b = ((unsigned)l & 511u) | (blk << 9) | (((unsigned)l >> 9) << 15);
        unsigned i = pinv18(b);
        float m = 1.f;
#pragma unroll
        for (int p = 0; p < 18; ++p) m *= ((i >> p) & 1u) ? s0[17 - p] : c0[17 - p];
        int k4 = __popc(i) & 3;
        float2 a;
        if      (k4 == 0) a = make_float2( m, 0.f);
        else if (k4 == 1) a = make_float2(0.f, -m);
        else if (k4 == 2) a = make_float2(-m, 0.f);
        else              a = make_float2(0.f,  m);
        t[PAD16(l)] = a;
    }
    __syncthreads();
#define RX1(a) pairR<cX1M[a], cX1M[(a)+1], 4096, 1024>(t, g[a], g[(a)+1]); __syncthreads();
    RX1(0) RX1(2) RX1(4) RX1(6) RX1(8) RX1(10) RX1(12) RX1(14)
    RX1(16) RX1(18) RX1(20) RX1(22) RX1(24) RX1(26) RX1(28) RX1(30)
#undef RX1
    singleR<cX1M[32], 4096, 1024>(t, g[32]);
    __syncthreads();
#pragma unroll
    for (int r = 0; r < 4; ++r) {
        int l = tid + 1024 * r;
        unsigned b = ((unsigned)l & 511u) | (blk << 9) | (((unsigned)l >> 9) << 15);
        out[b] = t[PAD16(l)];
    }
}

// ---- X2: 21 gates on span {7..17} + |amp|^2 + P^3 scatter; 128 x 512 ------
__global__ __launch_bounds__(512) void kX2(const float2* __restrict__ in, float* __restrict__ probs,
                                           const float* __restrict__ qw) {
    __shared__ float2 t[2176];
    __shared__ float2 g[21];
    int tid = threadIdx.x;
    if (tid < 21) { float th = qw[cX2A[tid]] * 0.5f; g[tid] = make_float2(cosf(th), sinf(th)); }
    unsigned blk = blockIdx.x;                 // global bits 0..6
#pragma unroll
    for (int r = 0; r < 4; ++r) {
        int l = tid + 512 * r;
        t[PAD16(l)] = in[blk | ((unsigned)l << 7)];
    }
    __syncthreads();
#define RX2(a) pairR<cX2M[a], cX2M[(a)+1], 2048, 512>(t, g[a], g[(a)+1]); __syncthreads();
    RX2(0) RX2(2) RX2(4) RX2(6) RX2(8) RX2(10) RX2(12) RX2(14) RX2(16) RX2(18)
#undef RX2
    singleR<cX2M[20], 2048, 512>(t, g[20]);
    __syncthreads();
#pragma unroll
    for (int r = 0; r < 4; ++r) {
        int l = tid + 512 * r;
        unsigned b = blk | ((unsigned)l << 7);
        unsigned pb = perm18(perm18(perm18(b)));
        float2 a = t[PAD16(l)];
        probs[pb] = a.x * a.x + a.y * a.y;
    }
}

// ---- k_mm: MFMA logits partials (R14-proven, plain) -----------------------
__global__ __launch_bounds__(256) void k_mm(const float* __restrict__ p0,
                                            const float* __restrict__ W,
                                            float* __restrict__ partial) {
    __shared__ short Wl[64][136];
    __shared__ short Pl[16][136];
    __shared__ unsigned Tsh[16];
    int tid = threadIdx.x;
    if (tid < 16) {
        unsigned v = (unsigned)tid;
#pragma unroll
        for (int r = 0; r < 4; ++r) v = perm18(v);
        Tsh[tid] = v;
    }
    __syncthreads();

    unsigned d00 = (unsigned)blockIdx.x * (CH * CPB);
    int wrow = tid >> 5;
    int wcol = (tid & 31) * 4;
    int prow = tid >> 7;
    int pcol = tid & 127;
    unsigned Tp[8];
#pragma unroll
    for (int t = 0; t < 8; ++t) Tp[t] = Tsh[prow + 2 * t];

    int lane = tid & 63, wv = tid >> 6;
    int arow = lane & 15, kg = (lane >> 4) * 8;
    f32x4 acc = {0.f, 0.f, 0.f, 0.f};
    float4 wr[8];
    float  pr[8];

#pragma unroll
    for (int t = 0; t < 8; ++t)
        wr[t] = *(const float4*)&W[(size_t)(wrow + 8 * t) * DIM + d00 + wcol];
#pragma unroll
    for (int t = 0; t < 8; ++t)
        pr[t] = p0[(d00 ^ (Tp[t] & ~127u)) + pcol];
#pragma unroll
    for (int t = 0; t < 8; ++t) {
        short4 b = make_short4(f2bf(wr[t].x), f2bf(wr[t].y), f2bf(wr[t].z), f2bf(wr[t].w));
        *(short4*)&Wl[wrow + 8 * t][wcol] = b;
    }
#pragma unroll
    for (int t = 0; t < 8; ++t)
        Pl[prow + 2 * t][pcol ^ (Tp[t] & 127u)] = f2bf(pr[t]);
    __syncthreads();

    for (int cc = 0; cc < CPB; ++cc) {
        if (cc + 1 < CPB) {
            unsigned d1 = d00 + (unsigned)(cc + 1) * CH;
#pragma unroll
            for (int t = 0; t < 8; ++t)
                wr[t] = *(const float4*)&W[(size_t)(wrow + 8 * t) * DIM + d1 + wcol];
#pragma unroll
            for (int t = 0; t < 8; ++t)
                pr[t] = p0[(d1 ^ (Tp[t] & ~127u)) + pcol];
        }
#pragma unroll
        for (int kk = 0; kk < 4; ++kk) {
            short8 a = *(const short8*)&Pl[arow][kk * 32 + kg];
            short8 b = *(const short8*)&Wl[16 * wv + arow][kk * 32 + kg];
            acc = __builtin_amdgcn_mfma_f32_16x16x32_bf16(a, b, acc, 0, 0, 0);
        }
        __syncthreads();
        if (cc + 1 < CPB) {
#pragma unroll
            for (int t = 0; t < 8; ++t) {
                short4 b = make_short4(f2bf(wr[t].x), f2bf(wr[t].y), f2bf(wr[t].z), f2bf(wr[t].w));
                *(short4*)&Wl[wrow + 8 * t][wcol] = b;
            }
#pragma unroll
            for (int t = 0; t < 8; ++t)
                Pl[prow + 2 * t][pcol ^ (Tp[t] & 127u)] = f2bf(pr[t]);
            __syncthreads();
        }
    }

    float* dst = partial + (size_t)blockIdx.x * 1024;
#pragma unroll
    for (int r = 0; r < 4; ++r) {
        int jrow = (lane >> 4) * 4 + r;
        dst[jrow * 64 + 16 * wv + (lane & 15)] = acc[r];
    }
}

// ---- finalize: reduce partials -> logits; lookup + sigmoid (R14-proven) ----
__global__ __launch_bounds__(256) void k_finalize(const float* __restrict__ partial,
                                                  const float* __restrict__ bias,
                                                  const int* __restrict__ x,
                                                  float* __restrict__ out) {
    int b = blockIdx.x;
    int tid = threadIdx.x;
    int ji = tid & 15, ci = tid >> 4;
    int jo = b * 16 + ji;
    float sum = 0.f;
#pragma unroll 8
    for (int c = ci; c < NMM; c += 16)
        sum += partial[(size_t)c * 1024 + jo];
    __shared__ float red[16][17];
    __shared__ float lg[16];
    __shared__ int sidx[32];
    red[ci][ji] = sum;
    if (tid < 32) {
        const int* xb = x + (size_t)tid * (16384 * 4);
        sidx[tid] = 8 * xb[0] + 4 * xb[1] + 2 * xb[2] + xb[3];
    }
    __syncthreads();
    if (ci == 0) {
        float s = 0.f;
#pragma unroll
        for (int k = 0; k < 16; ++k) s += red[k][ji];
        lg[ji] = s + bias[jo & 63];
    }
    __syncthreads();
    int myidx = b >> 2, o0 = (b & 3) * 16;
#pragma unroll
    for (int r = 0; r < 2; ++r) {
        int slot = tid + 256 * r;
        int bb = slot >> 4, k = slot & 15;
        if (sidx[bb] == myidx) {
            float z = lg[k];
            out[bb * 64 + o0 + k] = 1.f / (1.f + expf(-z));
        }
    }
}

extern "C" void kernel_launch(void* const* d_in, const int* in_sizes, int n_in,
                              void* d_out, int out_size, void* d_ws, size_t ws_size,
                              hipStream_t stream) {
    const int*   x    = (const int*)d_in[0];
    const float* qw   = (const float*)d_in[1];
    const float* W    = (const float*)d_in[2];
    const float* bias = (const float*)d_in[3];
    float* out = (float*)d_out;

    char* ws = (char*)d_ws;
    float2*   buf0    = (float2*)(ws + (1ull << 20));      // 2 MB
    float*    probs   = (float*)(ws + (8ull << 20));       // 1 MB
    float*    partial = (float*)(ws + (16ull << 20));      // 2 MB

    kX1<<<64, 1024, 0, stream>>>(buf0, qw);
    kX2<<<128, 512, 0, stream>>>(buf0, probs, qw);
    k_mm<<<NMM, 256, 0, stream>>>(probs, W, partial);
    k_finalize<<<64, 256, 0, stream>>>(partial, bias, x, out);
}